// Round 2
// baseline (839.215 us; speedup 1.0000x reference)
//
#include <hip/hip_runtime.h>
#include <hip/hip_bf16.h>
#include <math.h>

typedef __attribute__((ext_vector_type(8))) short bf16x8;
typedef __attribute__((ext_vector_type(4))) float f32x4;

#define EPW 8      // edges per wave
#define XS 40      // staged image row stride in ushorts per pixel (80B, 16B-aligned)
#define XROWS 65   // 64 pixel rows + 1 zero row (row 64) for padding taps
#define WST 296    // staged weight row stride in ushorts per co (592B, 16B-aligned)

__device__ __forceinline__ unsigned short bf16bits(float f) {
    union { __hip_bfloat16 h; unsigned short u; } cv;
    cv.h = __float2bfloat16(f);
    return cv.u;
}

// ---- split staging: global->regs (issue early), regs->LDS (cvt+write late) ----
__device__ __forceinline__ void load_img(const float* __restrict__ g, float* r, int lane) {
    #pragma unroll
    for (int i = 0; i < 32; ++i) r[i] = g[i * 64 + lane];   // coalesced: lane = pixel
}

__device__ __forceinline__ void write_img(const float* r, unsigned short* xw, int lane) {
    #pragma unroll
    for (int i = 0; i < 16; ++i) {
        unsigned int pk = (unsigned int)bf16bits(r[2 * i]) |
                          ((unsigned int)bf16bits(r[2 * i + 1]) << 16);
        *(unsigned int*)&xw[lane * XS + 2 * i] = pk;   // x_t[pix=lane][ci pair]
    }
}

// One 3x3 conv as GEMM: C[32co x 64pix] = W[32 x 288] * im2col[288 x 64].
// Padding taps read LDS row 64 (all zeros, broadcast) -> no per-fragment cndmask.
__device__ __forceinline__ void conv_mfma(const unsigned short* __restrict__ xw,
                                          const unsigned short* __restrict__ wl,
                                          int m, int quad, f32x4 acc[2][4]) {
    #pragma unroll
    for (int kb = 0; kb < 9; ++kb) {
        const int kh = kb / 3, kw = kb - kh * 3;
        bf16x8 a0 = *(const bf16x8*)&wl[ m        * WST + kb * 32 + quad * 8];
        bf16x8 a1 = *(const bf16x8*)&wl[(m + 16)  * WST + kb * 32 + quad * 8];
        #pragma unroll
        for (int nt = 0; nt < 4; ++nt) {
            const int p  = nt * 16 + m;
            const int ih = (p >> 3) + kh - 1;
            const int iw = (p & 7) + kw - 1;
            const bool valid = ((unsigned)ih < 8u) && ((unsigned)iw < 8u);
            const int pixp = valid ? (ih * 8 + iw) : 64;      // row 64 = zeros
            bf16x8 b = *(const bf16x8*)&xw[pixp * XS + quad * 8];
            acc[0][nt] = __builtin_amdgcn_mfma_f32_16x16x32_bf16(a0, b, acc[0][nt], 0, 0, 0);
            acc[1][nt] = __builtin_amdgcn_mfma_f32_16x16x32_bf16(a1, b, acc[1][nt], 0, 0, 0);
        }
    }
}

// Fused per-edge kernel, templated on waves/block.
// Dynamic LDS layout (ushorts): [0]=w_edge[32*WST], [1]=w_node[32*WST],
// then per-wave image buffers [XROWS*XS].
template<int WAVES_T>
__global__ __launch_bounds__(WAVES_T * 64, 4)
void fused_edge_kernel(const float* __restrict__ input,
                       const int* __restrict__ srcv,
                       const float* __restrict__ e,
                       const float* __restrict__ w_node,
                       const float* __restrict__ w_edge,
                       float* __restrict__ out,
                       int n_edges)
{
    extern __shared__ unsigned short smem_u16[];
    unsigned short* wl0 = smem_u16;                  // w_edge
    unsigned short* wl1 = smem_u16 + 32 * WST;       // w_node

    const int t = threadIdx.x;
    const int lane = t & 63;
    const int wave = t >> 6;
    unsigned short* xw = smem_u16 + 2 * 32 * WST + wave * (XROWS * XS);

    // Stage both weight tensors: fp32 OIHW -> bf16 [co][(kh*3+kw)*32 + ci]
    for (int i = t; i < 9216; i += WAVES_T * 64) {
        int co  = i / 288;
        int rem = i - co * 288;
        int ci  = rem / 9;
        int khw = rem - ci * 9;
        int dst = co * WST + khw * 32 + ci;
        wl0[dst] = bf16bits(w_edge[i]);
        wl1[dst] = bf16bits(w_node[i]);
    }
    // zero row 64 of this wave's image buffer (padding-tap source)
    if (lane < XS) xw[64 * XS + lane] = 0;
    __syncthreads();  // only barrier; everything after is wave-private

    const int m    = lane & 15;
    const int quad = lane >> 4;

    const int img0 = (blockIdx.x * WAVES_T + wave) * EPW;

    float ereg[32];
    int src = 0;
    if (img0 < n_edges) {
        load_img(e + (size_t)img0 * 2048, ereg, lane);   // prologue: e[img0] in flight
        src = srcv[img0];
    }

    for (int j = 0; j < EPW; ++j) {
        const int img = img0 + j;
        if (img >= n_edges) break;   // wave-uniform

        f32x4 accz[2][4], acct[2][4];
        #pragma unroll
        for (int a = 0; a < 2; ++a)
            #pragma unroll
            for (int b = 0; b < 4; ++b) { accz[a][b] = (f32x4)0.f; acct[a][b] = (f32x4)0.f; }

        // stage e[img] (regs -> LDS), then issue input[src] loads so their
        // latency hides under conv1's 72 MFMAs (vmcnt vs lgkm: independent).
        write_img(ereg, xw, lane);
        float ireg[32];
        load_img(input + (size_t)src * 2048, ireg, lane);
        if (j + 1 < EPW && img + 1 < n_edges) src = srcv[img + 1];   // prefetch next src
        conv_mfma(xw, wl0, m, quad, accz);          // z = conv3x3(e, w_edge)

        // stage input image, then issue next e loads hidden under conv2+epilogue.
        write_img(ireg, xw, lane);
        if (j + 1 < EPW && img + 1 < n_edges)
            load_img(e + (size_t)(img + 1) * 2048, ereg, lane);
        conv_mfma(xw, wl1, m, quad, acct);          // th = conv3x3(input[src], w_node)

        // out = elu(th * z); C/D layout: row(co) = quad*4 + r (+16*mt), col(pix) = m (+16*nt)
        float* op = out + (size_t)img * 2048;
        #pragma unroll
        for (int mt = 0; mt < 2; ++mt)
            #pragma unroll
            for (int nt = 0; nt < 4; ++nt)
                #pragma unroll
                for (int r = 0; r < 4; ++r) {
                    const int co = mt * 16 + quad * 4 + r;
                    const int p  = nt * 16 + m;
                    float v = accz[mt][nt][r] * acct[mt][nt][r];
                    op[co * 64 + p] = v > 0.f ? v : (__expf(v) - 1.f);
                }
    }
}

extern "C" void kernel_launch(void* const* d_in, const int* in_sizes, int n_in,
                              void* d_out, int out_size, void* d_ws, size_t ws_size,
                              hipStream_t stream)
{
    // setup_inputs order: input, edge_sources, e, w_node, w_edge
    const float* input        = (const float*)d_in[0];
    const int*   edge_sources = (const int*)  d_in[1];
    const float* e            = (const float*)d_in[2];
    const float* w_node       = (const float*)d_in[3];
    const float* w_edge       = (const float*)d_in[4];
    float* out = (float*)d_out;
    (void)d_ws; (void)ws_size;

    const int n_edges = in_sizes[1];   // 32768

    // Preferred: 8 waves/block, dynamic LDS 79.5 KB -> 2 blocks/CU, 16 waves/CU
    // (4 waves/SIMD; VGPR capped 128 by __launch_bounds__(512,4)).
    const size_t lds8 = (size_t)(2 * 32 * WST + 8 * XROWS * XS) * sizeof(unsigned short);
    // Fallback: 4 waves/block, 58.7 KB (<64 KB default dynamic limit), proven geometry.
    const size_t lds4 = (size_t)(2 * 32 * WST + 4 * XROWS * XS) * sizeof(unsigned short);

    static int use8 = -1;   // resolve once; hipFuncSetAttribute is host-side & capture-safe
    if (use8 < 0) {
        hipError_t err = hipFuncSetAttribute(
            reinterpret_cast<const void*>(&fused_edge_kernel<8>),
            hipFuncAttributeMaxDynamicSharedMemorySize, (int)lds8);
        use8 = (err == hipSuccess) ? 1 : 0;
    }

    if (use8) {
        const int per_block = 8 * EPW;   // 64 edges/block
        const int grid = (n_edges + per_block - 1) / per_block;   // 512 blocks
        fused_edge_kernel<8><<<dim3(grid), dim3(512), lds8, stream>>>(
            input, edge_sources, e, w_node, w_edge, out, n_edges);
    } else {
        const int per_block = 4 * EPW;   // 32 edges/block
        const int grid = (n_edges + per_block - 1) / per_block;   // 1024 blocks
        fused_edge_kernel<4><<<dim3(grid), dim3(256), lds4, stream>>>(
            input, edge_sources, e, w_node, w_edge, out, n_edges);
    }
}